// Round 6
// baseline (316.860 us; speedup 1.0000x reference)
//
#include <hip/hip_runtime.h>
#include <hip/hip_bf16.h>

// Shapes (fixed): B=1, S=2048, HID=2048, NH=16, NKV=4, HD=128
// Inputs: fp32. Output: fp32. Internal compute: bf16 MFMA, fp32 accumulate.
typedef __bf16 bf16_t;
typedef __attribute__((ext_vector_type(8))) __bf16 bf16x8;
typedef __attribute__((ext_vector_type(4))) float f32x4;

#define S_LEN 2048
#define HID 2048
#define NH 16
#define NKV 4
#define HD 128

__device__ __forceinline__ bf16x8 cvt2x4(float4 a, float4 b) {
    bf16x8 o;
    o[0]=(bf16_t)a.x; o[1]=(bf16_t)a.y; o[2]=(bf16_t)a.z; o[3]=(bf16_t)a.w;
    o[4]=(bf16_t)b.x; o[5]=(bf16_t)b.y; o[6]=(bf16_t)b.z; o[7]=(bf16_t)b.w;
    return o;
}

// ---------------------------------------------------------------------------
// Fused weight conversion: [wq | wk | wv] fp32 -> contiguous bf16 (3072 x 2048)
// ---------------------------------------------------------------------------
__global__ __launch_bounds__(256) void cvt_w3(const float* __restrict__ wq,
                                              const float* __restrict__ wk,
                                              const float* __restrict__ wv,
                                              bf16_t* __restrict__ out)
{
    int i = (blockIdx.x * 256 + threadIdx.x) * 8;
    const float* src; int off;
    if (i < 4 * 1024 * 1024)      { src = wq; off = i; }
    else if (i < 5 * 1024 * 1024) { src = wk; off = i - 4 * 1024 * 1024; }
    else                          { src = wv; off = i - 5 * 1024 * 1024; }
    float4 a = *(const float4*)&src[off];
    float4 b = *(const float4*)&src[off + 4];
    *(bf16x8*)&out[i] = cvt2x4(a, b);
}

// ---------------------------------------------------------------------------
// Fused QKV GEMM: A = x (fp32, inline-cvt), B = [wq;wk;wv] bf16 (N=3072).
// 128x64 tile, BK=64, 16 MFMA/iter, register-prefetch staging (no gll ->
// no naked vmcnt drain at the barrier), padded LDS (stride 72, 2-way free).
// XCD swizzle: bid%8 = XCD; each XCD owns 2 m-tile rows -> A locks into L2.
// ---------------------------------------------------------------------------
__global__ __launch_bounds__(256, 3) void gemm_qkv(
    const float* __restrict__ A, const bf16_t* __restrict__ B,
    bf16_t* __restrict__ Cq, bf16_t* __restrict__ Ck, bf16_t* __restrict__ Cvt,
    int M, int K)
{
    __shared__ __align__(16) bf16_t sA[128 * 72];
    __shared__ __align__(16) bf16_t sB[64 * 72];

    const int tid  = threadIdx.x;
    const int lane = tid & 63;
    const int wave = tid >> 6;
    const int l16  = lane & 15;
    const int quad = lane >> 4;

    // XCD-locality swizzle: 768 blocks, 96 per XCD = 2 m-rows x 48 n-tiles
    const int bid = blockIdx.x;
    const int xcd = bid & 7;
    const int idx = bid >> 3;
    const int m0 = (xcd * 2 + idx / 48) * 128;
    const int n0 = (idx % 48) * 64;

    const int wm = (wave >> 1) * 64;
    const int wn = (wave & 1) * 32;

    // A staging: thread -> row at=tid>>1, fp32 col half ah=(tid&1)*32
    const int at = tid >> 1, ah = tid & 1;
    const float* gA = A + (size_t)(m0 + at) * K + ah * 32;
    bf16_t* lA = &sA[at * 72 + ah * 32];
    // B staging: thread -> row bt=tid>>2, bf16 col quarter bq=(tid&3)*16
    const int bt = tid >> 2, bq = tid & 3;
    const bf16_t* gB = B + (size_t)(n0 + bt) * K + bq * 16;
    bf16_t* lB = &sB[bt * 72 + bq * 16];

    f32x4 acc[4][2] = {};

    float4 pa[8];
    bf16x8 pb[2];
#pragma unroll
    for (int u = 0; u < 8; u++) pa[u] = *(const float4*)(gA + u * 4);
#pragma unroll
    for (int u = 0; u < 2; u++) pb[u] = *(const bf16x8*)(gB + u * 8);

    for (int k0 = 0; k0 < K; k0 += 64) {
        __syncthreads();                       // prev LDS reads done
#pragma unroll
        for (int q = 0; q < 4; q++)
            *(bf16x8*)(lA + q * 8) = cvt2x4(pa[2 * q], pa[2 * q + 1]);
#pragma unroll
        for (int u = 0; u < 2; u++)
            *(bf16x8*)(lB + u * 8) = pb[u];
        __syncthreads();                       // tiles visible

        if (k0 + 64 < K) {                     // prefetch next tiles now;
            gA += 64; gB += 64;                // they land during the MFMAs
#pragma unroll
            for (int u = 0; u < 8; u++) pa[u] = *(const float4*)(gA + u * 4);
#pragma unroll
            for (int u = 0; u < 2; u++) pb[u] = *(const bf16x8*)(gB + u * 8);
        }

#pragma unroll
        for (int kc = 0; kc < 2; kc++) {
            bf16x8 af[4], bfv[2];
#pragma unroll
            for (int i = 0; i < 4; i++)
                af[i] = *(bf16x8*)&sA[(wm + i * 16 + l16) * 72 + kc * 32 + quad * 8];
#pragma unroll
            for (int j = 0; j < 2; j++)
                bfv[j] = *(bf16x8*)&sB[(wn + j * 16 + l16) * 72 + kc * 32 + quad * 8];
#pragma unroll
            for (int i = 0; i < 4; i++)
#pragma unroll
                for (int j = 0; j < 2; j++)
                    acc[i][j] = __builtin_amdgcn_mfma_f32_16x16x32_bf16(af[i], bfv[j], acc[i][j], 0, 0, 0);
        }
    }

    // epilogue, q/k/v routed (C/D layout: col=lane&15, row=quad*4+r)
#pragma unroll
    for (int i = 0; i < 4; i++) {
        int rowb = m0 + wm + i * 16 + quad * 4;
#pragma unroll
        for (int j = 0; j < 2; j++) {
            int col = n0 + wn + j * 16 + l16;
#pragma unroll
            for (int r = 0; r < 4; r++) {
                float v = acc[i][j][r];
                int row = rowb + r;
                if (col < 2048)      Cq[(size_t)row * 2048 + col] = (bf16_t)v;
                else if (col < 2560) Ck[(size_t)row * 512 + (col - 2048)] = (bf16_t)v;
                else                 Cvt[(size_t)(col - 2560) * S_LEN + row] = (bf16_t)v;
            }
        }
    }
}

// ---------------------------------------------------------------------------
// Output GEMM: C = A[M,K](bf16) * B[N,K]^T(fp32, inline-cvt) -> fp32.
// Same 128x64/BK=64 register-prefetch structure; XCD swizzle (512 blocks).
// ---------------------------------------------------------------------------
__global__ __launch_bounds__(256, 3) void gemm_wo(
    const bf16_t* __restrict__ A, const float* __restrict__ B,
    float* __restrict__ C, int M, int N, int K)
{
    __shared__ __align__(16) bf16_t sA[128 * 72];
    __shared__ __align__(16) bf16_t sB[64 * 72];

    const int tid  = threadIdx.x;
    const int lane = tid & 63;
    const int wave = tid >> 6;
    const int l16  = lane & 15;
    const int quad = lane >> 4;

    // 512 blocks, 64 per XCD = 2 m-rows x 32 n-tiles
    const int bid = blockIdx.x;
    const int xcd = bid & 7;
    const int idx = bid >> 3;
    const int m0 = (xcd * 2 + idx / 32) * 128;
    const int n0 = (idx % 32) * 64;

    const int wm = (wave >> 1) * 64;
    const int wn = (wave & 1) * 32;

    const int at = tid >> 1, ah = tid & 1;   // A: bf16, 32 elems/thread
    const bf16_t* gA = A + (size_t)(m0 + at) * K + ah * 32;
    bf16_t* lA = &sA[at * 72 + ah * 32];
    const int bt = tid >> 2, bq = tid & 3;   // B: fp32, 16 elems/thread
    const float* gB = B + (size_t)(n0 + bt) * K + bq * 16;
    bf16_t* lB = &sB[bt * 72 + bq * 16];

    f32x4 acc[4][2] = {};

    bf16x8 pa[4];
    float4 pb[4];
#pragma unroll
    for (int u = 0; u < 4; u++) pa[u] = *(const bf16x8*)(gA + u * 8);
#pragma unroll
    for (int u = 0; u < 4; u++) pb[u] = *(const float4*)(gB + u * 4);

    for (int k0 = 0; k0 < K; k0 += 64) {
        __syncthreads();
#pragma unroll
        for (int u = 0; u < 4; u++)
            *(bf16x8*)(lA + u * 8) = pa[u];
#pragma unroll
        for (int q = 0; q < 2; q++)
            *(bf16x8*)(lB + q * 8) = cvt2x4(pb[2 * q], pb[2 * q + 1]);
        __syncthreads();

        if (k0 + 64 < K) {
            gA += 64; gB += 64;
#pragma unroll
            for (int u = 0; u < 4; u++) pa[u] = *(const bf16x8*)(gA + u * 8);
#pragma unroll
            for (int u = 0; u < 4; u++) pb[u] = *(const float4*)(gB + u * 4);
        }

#pragma unroll
        for (int kc = 0; kc < 2; kc++) {
            bf16x8 af[4], bfv[2];
#pragma unroll
            for (int i = 0; i < 4; i++)
                af[i] = *(bf16x8*)&sA[(wm + i * 16 + l16) * 72 + kc * 32 + quad * 8];
#pragma unroll
            for (int j = 0; j < 2; j++)
                bfv[j] = *(bf16x8*)&sB[(wn + j * 16 + l16) * 72 + kc * 32 + quad * 8];
#pragma unroll
            for (int i = 0; i < 4; i++)
#pragma unroll
                for (int j = 0; j < 2; j++)
                    acc[i][j] = __builtin_amdgcn_mfma_f32_16x16x32_bf16(af[i], bfv[j], acc[i][j], 0, 0, 0);
        }
    }

#pragma unroll
    for (int i = 0; i < 4; i++) {
        int row = m0 + wm + i * 16 + quad * 4;
#pragma unroll
        for (int j = 0; j < 2; j++) {
            int col = n0 + wn + j * 16 + l16;
#pragma unroll
            for (int r = 0; r < 4; r++)
                C[(size_t)(row + r) * N + col] = acc[i][j][r];
        }
    }
}

// ---------------------------------------------------------------------------
// Fused RoPE over q (16 heads) and k (4 heads): grid (S, 5), block 128.
// ---------------------------------------------------------------------------
__global__ void rope_all(bf16_t* __restrict__ Qh, bf16_t* __restrict__ Kh,
                         const float* __restrict__ cosb, const float* __restrict__ sinb)
{
    int s = blockIdx.x;
    int grp = blockIdx.y;           // 0..3: q head groups; 4: k heads
    int sub = threadIdx.x >> 5;
    int i = threadIdx.x & 31;
    bf16_t* row = (grp < 4) ? (Qh + ((size_t)s * NH + grp * 4 + sub) * HD)
                            : (Kh + ((size_t)s * NKV + sub) * HD);
    float x0 = (float)row[2 * i];
    float x1 = (float)row[2 * i + 1];
    float p0 = (float)row[64 + 2 * i];
    float p1 = (float)row[64 + 2 * i + 1];
    float c0 = cosb[s * HD + 2 * i];
    float c1 = cosb[s * HD + 2 * i + 1];
    float n0 = sinb[s * HD + 2 * i];
    float n1 = sinb[s * HD + 2 * i + 1];
    float r0 = -x1, r1 = x0;
    row[2 * i]          = (bf16_t)(r0 * c0 + p0 * n0);
    row[2 * i + 1]      = (bf16_t)(r1 * c1 + p1 * n1);
    row[64 + 2 * i]     = (bf16_t)(-r0 * n0 + p0 * c0);
    row[64 + 2 * i + 1] = (bf16_t)(-r1 * n1 + p1 * c1);
}

// ---------------------------------------------------------------------------
// Flash attention v3 (unchanged from R5 — kept identical so the next profile
// exposes its true cost). Block = (16 q-rows, 1 kv-head, 4 q-heads).
// ---------------------------------------------------------------------------
__global__ __launch_bounds__(256, 2) void flash_attn3(
    const bf16_t* Q, const bf16_t* __restrict__ Kb,
    const bf16_t* __restrict__ VT, bf16_t* O, int S)
{
    __shared__ __align__(16) bf16_t sK[64 * 136];
    __shared__ __align__(16) bf16_t sVT[128 * 72];
    __shared__ __align__(16) bf16_t sP[4][16 * 72];

    const int kvh = blockIdx.y;
    const int q0  = blockIdx.x * 16;
    const int tid = threadIdx.x, lane = tid & 63, wave = tid >> 6;
    const int l16 = lane & 15, quad = lane >> 4;
    const int head = kvh * 4 + wave;
    const float scale = 0.08838834764831845f;  // 1/sqrt(128)

    bf16x8 qf[4];
#pragma unroll
    for (int c = 0; c < 4; c++)
        qf[c] = *(const bf16x8*)&Q[(size_t)(q0 + l16) * HID + head * HD + c * 32 + quad * 8];

    f32x4 oacc[8] = {};
    float lsum[4] = {};
    const int s_row = q0 + quad * 4;
    const int nkt = (blockIdx.x >> 2) + 1;

    int krow[4], kcol[4], vrow[4], vcol[4];
#pragma unroll
    for (int it = 0; it < 4; it++) {
        int c = tid + 256 * it;
        krow[it] = c >> 4; kcol[it] = (c & 15) * 8;
        vrow[it] = c >> 3; vcol[it] = (c & 7) * 8;
    }

    bf16x8 kpre[4], vpre[4];
#pragma unroll
    for (int it = 0; it < 4; it++) {
        kpre[it] = *(const bf16x8*)&Kb[(size_t)krow[it] * (NKV * HD) + kvh * HD + kcol[it]];
        vpre[it] = *(const bf16x8*)&VT[((size_t)kvh * HD + vrow[it]) * S + vcol[it]];
    }

    for (int kt = 0; kt < nkt; kt++) {
        const int t0 = kt * 64;
        __syncthreads();
#pragma unroll
        for (int it = 0; it < 4; it++) {
            *(bf16x8*)&sK[krow[it] * 136 + kcol[it]] = kpre[it];
            *(bf16x8*)&sVT[vrow[it] * 72 + vcol[it]] = vpre[it];
        }
        __syncthreads();

        if (kt + 1 < nkt) {
            const int t1 = t0 + 64;
#pragma unroll
            for (int it = 0; it < 4; it++) {
                kpre[it] = *(const bf16x8*)&Kb[(size_t)(t1 + krow[it]) * (NKV * HD) + kvh * HD + kcol[it]];
                vpre[it] = *(const bf16x8*)&VT[((size_t)kvh * HD + vrow[it]) * S + t1 + vcol[it]];
            }
        }

        f32x4 sc[4];
#pragma unroll
        for (int nt = 0; nt < 4; nt++) {
            f32x4 d = {};
#pragma unroll
            for (int c = 0; c < 4; c++) {
                bf16x8 kf = *(bf16x8*)&sK[(nt * 16 + l16) * 136 + c * 32 + quad * 8];
                d = __builtin_amdgcn_mfma_f32_16x16x32_bf16(qf[c], kf, d, 0, 0, 0);
            }
            sc[nt] = d;
        }

#pragma unroll
        for (int nt = 0; nt < 4; nt++) {
            int t = t0 + nt * 16 + l16;
#pragma unroll
            for (int r = 0; r < 4; r++) {
                float p = (t <= s_row + r) ? __expf(sc[nt][r] * scale) : 0.0f;
                lsum[r] += p;
                sP[wave][(quad * 4 + r) * 72 + nt * 16 + l16] = (bf16_t)p;
            }
        }
        bf16x8 pa[2];
#pragma unroll
        for (int kc = 0; kc < 2; kc++)
            pa[kc] = *(bf16x8*)&sP[wave][l16 * 72 + kc * 32 + quad * 8];

#pragma unroll
        for (int dt = 0; dt < 8; dt++)
#pragma unroll
            for (int kc = 0; kc < 2; kc++) {
                bf16x8 vf = *(bf16x8*)&sVT[(dt * 16 + l16) * 72 + kc * 32 + quad * 8];
                oacc[dt] = __builtin_amdgcn_mfma_f32_16x16x32_bf16(pa[kc], vf, oacc[dt], 0, 0, 0);
            }
    }

#pragma unroll
    for (int r = 0; r < 4; r++) {
        float s = lsum[r];
        for (int m = 1; m < 16; m <<= 1)
            s += __shfl_xor(s, m, 64);
        float inv = 1.0f / s;
        int srow = s_row + r;
#pragma unroll
        for (int dt = 0; dt < 8; dt++)
            O[(size_t)srow * HID + head * HD + dt * 16 + l16] = (bf16_t)(oacc[dt][r] * inv);
    }
}

// ---------------------------------------------------------------------------
extern "C" void kernel_launch(void* const* d_in, const int* in_sizes, int n_in,
                              void* d_out, int out_size, void* d_ws, size_t ws_size,
                              hipStream_t stream)
{
    const float* x    = (const float*)d_in[0];
    const float* cosb = (const float*)d_in[1];
    const float* sinb = (const float*)d_in[2];
    const float* wq   = (const float*)d_in[3];
    const float* wk   = (const float*)d_in[4];
    const float* wv   = (const float*)d_in[5];
    const float* wo   = (const float*)d_in[6];
    float* out = (float*)d_out;

    // Workspace (24 MB):
    char* ws = (char*)d_ws;
    bf16_t* wb = (bf16_t*)(ws);                              // 0..12 MB: [wq;wk;wv] bf16
    bf16_t* qh = (bf16_t*)(ws + (size_t)12 * 1024 * 1024);   // 12..20 MB: q / attn-out
    bf16_t* kh = (bf16_t*)(ws + (size_t)20 * 1024 * 1024);   // 20..22 MB: k
    bf16_t* vT = (bf16_t*)(ws + (size_t)22 * 1024 * 1024);   // 22..24 MB: v^T

    // 1) weights -> bf16
    cvt_w3<<<6 * 1024 * 1024 / (256 * 8), 256, 0, stream>>>(wq, wk, wv, wb);

    // 2) fused QKV GEMM (x fp32 inline-cvt), XCD-swizzled, routed outputs
    gemm_qkv<<<768, 256, 0, stream>>>(x, wb, qh, kh, vT, S_LEN, HID);

    // 3) RoPE on q + k
    rope_all<<<dim3(S_LEN, 5), 128, 0, stream>>>(qh, kh, cosb, sinb);

    // 4) causal GQA flash attention (O aliases Q)
    flash_attn3<<<dim3(S_LEN / 16, NKV), 256, 0, stream>>>(qh, kh, vT, qh, S_LEN);

    // 5) out = attn_out @ wo^T (wo fp32 inline-cvt) -> fp32 d_out
    gemm_wo<<<512, 256, 0, stream>>>(qh, wo, out, S_LEN, HID, HID);
}

// Round 7
// 260.642 us; speedup vs baseline: 1.2157x; 1.2157x over previous
//
#include <hip/hip_runtime.h>
#include <hip/hip_bf16.h>

// Shapes (fixed): B=1, S=2048, HID=2048, NH=16, NKV=4, HD=128
// Inputs: fp32. Output: fp32. Internal compute: bf16 MFMA, fp32 accumulate.
typedef __bf16 bf16_t;
typedef __attribute__((ext_vector_type(8))) __bf16 bf16x8;
typedef __attribute__((ext_vector_type(4))) float f32x4;

#define S_LEN 2048
#define HID 2048
#define NH 16
#define NKV 4
#define HD 128

__device__ __forceinline__ void gll16(const bf16_t* g, bf16_t* l) {
    __builtin_amdgcn_global_load_lds(
        (const __attribute__((address_space(1))) unsigned int*)g,
        (__attribute__((address_space(3))) unsigned int*)l, 16, 0, 0);
}

__device__ __forceinline__ bf16x8 cvt2x4(float4 a, float4 b) {
    bf16x8 o;
    o[0]=(bf16_t)a.x; o[1]=(bf16_t)a.y; o[2]=(bf16_t)a.z; o[3]=(bf16_t)a.w;
    o[4]=(bf16_t)b.x; o[5]=(bf16_t)b.y; o[6]=(bf16_t)b.z; o[7]=(bf16_t)b.w;
    return o;
}

// ---------------------------------------------------------------------------
__global__ __launch_bounds__(256) void cvt_f32_bf16(const float* __restrict__ in,
                                                    bf16_t* __restrict__ out, int n)
{
    int i = (blockIdx.x * 256 + threadIdx.x) * 8;
    if (i >= n) return;
    float4 a = *(const float4*)&in[i];
    float4 b = *(const float4*)&in[i + 4];
    *(bf16x8*)&out[i] = cvt2x4(a, b);
}

// Fused weight conversion: [wq | wk | wv] fp32 -> contiguous bf16 (3072 x 2048)
__global__ __launch_bounds__(256) void cvt_w3(const float* __restrict__ wq,
                                              const float* __restrict__ wk,
                                              const float* __restrict__ wv,
                                              bf16_t* __restrict__ out)
{
    int i = (blockIdx.x * 256 + threadIdx.x) * 8;
    const float* src; int off;
    if (i < 4 * 1024 * 1024)      { src = wq; off = i; }
    else if (i < 5 * 1024 * 1024) { src = wk; off = i - 4 * 1024 * 1024; }
    else                          { src = wv; off = i - 5 * 1024 * 1024; }
    float4 a = *(const float4*)&src[off];
    float4 b = *(const float4*)&src[off + 4];
    *(bf16x8*)&out[i] = cvt2x4(a, b);
}

// ---------------------------------------------------------------------------
// m97-recipe NT GEMM: C[M,N] = A[M,K] * B[N,K]^T, all-bf16, fp32 accum.
// 128x128 tile, BK=64, 4 waves (2x2, 64x64 wave tile, 4x4 acc), 32 MFMA/iter,
// global_load_lds width-16 staging for A and B (4+4 instr/wave/iter),
// unpadded LDS with XOR-of-16B-chunk swizzle (global vaddr permuted per lane;
// LDS write stays gll-contiguous). Plain 2D grid (XCD swizzle reverted).
// MODE 0: C fp32 row-major. MODE 1: qkv routing (C=q bf16 / Ck / Cvt^T).
// ---------------------------------------------------------------------------
template<int MODE, typename CT>
__global__ __launch_bounds__(256, 2) void gemm128(
    const bf16_t* __restrict__ A, const bf16_t* __restrict__ B,
    CT* __restrict__ C, bf16_t* __restrict__ CkP, bf16_t* __restrict__ CvtP,
    int N, int K)
{
    __shared__ __align__(16) bf16_t sA[128 * 64];   // 16 KB, row-major, no pad
    __shared__ __align__(16) bf16_t sB[128 * 64];

    const int tid = threadIdx.x, lane = tid & 63, wave = tid >> 6;
    const int l16 = lane & 15, quad = lane >> 4;
    const int m0 = blockIdx.y * 128, n0 = blockIdx.x * 128;
    const int wm = (wave >> 1) * 64, wn = (wave & 1) * 64;

    // staging: physical 16B chunk p -> (row=p>>3, pc=p&7); logical chunk
    // lc = pc ^ (row&7). Each wave stages 4 chunks-groups of A and of B.
    const bf16_t* gA[4]; const bf16_t* gB[4];
    bf16_t* lA[4]; bf16_t* lB[4];
#pragma unroll
    for (int t = 0; t < 4; t++) {
        int p = (wave * 4 + t) * 64 + lane;
        int row = p >> 3;
        int lc = (p & 7) ^ (row & 7);
        gA[t] = A + (size_t)(m0 + row) * K + lc * 8;
        gB[t] = B + (size_t)(n0 + row) * K + lc * 8;
        lA[t] = &sA[(wave * 4 + t) * 512];   // wave-uniform base; hw adds lane*16
        lB[t] = &sB[(wave * 4 + t) * 512];
    }

    // fragment read offsets (element units), swizzle applied
    int offA[2][4], offB[2][4];
#pragma unroll
    for (int kc = 0; kc < 2; kc++)
#pragma unroll
        for (int i = 0; i < 4; i++) {
            int rm = wm + i * 16 + l16;
            offA[kc][i] = rm * 64 + (((kc * 4 + quad) ^ (rm & 7)) * 8);
            int rn = wn + i * 16 + l16;
            offB[kc][i] = rn * 64 + (((kc * 4 + quad) ^ (rn & 7)) * 8);
        }

    f32x4 acc[4][4] = {};

    for (int k0 = 0; k0 < K; k0 += 64) {
        __syncthreads();                     // prev LDS reads done
#pragma unroll
        for (int t = 0; t < 4; t++) {
            gll16(gA[t], lA[t]);
            gll16(gB[t], lB[t]);
            gA[t] += 64; gB[t] += 64;
        }
        __syncthreads();                     // vmcnt(0) drained -> visible

#pragma unroll
        for (int kc = 0; kc < 2; kc++) {
            bf16x8 af[4], bfv[4];
#pragma unroll
            for (int i = 0; i < 4; i++) af[i] = *(bf16x8*)&sA[offA[kc][i]];
#pragma unroll
            for (int j = 0; j < 4; j++) bfv[j] = *(bf16x8*)&sB[offB[kc][j]];
#pragma unroll
            for (int i = 0; i < 4; i++)
#pragma unroll
                for (int j = 0; j < 4; j++)
                    acc[i][j] = __builtin_amdgcn_mfma_f32_16x16x32_bf16(af[i], bfv[j], acc[i][j], 0, 0, 0);
        }
    }

    // epilogue: C/D layout col=lane&15, row=quad*4+r  [m89-verified]
#pragma unroll
    for (int i = 0; i < 4; i++) {
        int rowb = m0 + wm + i * 16 + quad * 4;
#pragma unroll
        for (int j = 0; j < 4; j++) {
            int col = n0 + wn + j * 16 + l16;
#pragma unroll
            for (int r = 0; r < 4; r++) {
                float v = acc[i][j][r];
                int row = rowb + r;
                if (MODE == 0) {
                    C[(size_t)row * N + col] = (CT)v;
                } else {
                    if (col < 2048)      C[(size_t)row * 2048 + col] = (CT)v;
                    else if (col < 2560) CkP[(size_t)row * 512 + (col - 2048)] = (bf16_t)v;
                    else                 CvtP[(size_t)(col - 2560) * S_LEN + row] = (bf16_t)v;
                }
            }
        }
    }
}

// ---------------------------------------------------------------------------
// Fused RoPE over q (16 heads) and k (4 heads): grid (S, 5), block 128.
// ---------------------------------------------------------------------------
__global__ void rope_all(bf16_t* __restrict__ Qh, bf16_t* __restrict__ Kh,
                         const float* __restrict__ cosb, const float* __restrict__ sinb)
{
    int s = blockIdx.x;
    int grp = blockIdx.y;           // 0..3: q head groups; 4: k heads
    int sub = threadIdx.x >> 5;
    int i = threadIdx.x & 31;
    bf16_t* row = (grp < 4) ? (Qh + ((size_t)s * NH + grp * 4 + sub) * HD)
                            : (Kh + ((size_t)s * NKV + sub) * HD);
    float x0 = (float)row[2 * i];
    float x1 = (float)row[2 * i + 1];
    float p0 = (float)row[64 + 2 * i];
    float p1 = (float)row[64 + 2 * i + 1];
    float c0 = cosb[s * HD + 2 * i];
    float c1 = cosb[s * HD + 2 * i + 1];
    float n0 = sinb[s * HD + 2 * i];
    float n1 = sinb[s * HD + 2 * i + 1];
    float r0 = -x1, r1 = x0;
    row[2 * i]          = (bf16_t)(r0 * c0 + p0 * n0);
    row[2 * i + 1]      = (bf16_t)(r1 * c1 + p1 * n1);
    row[64 + 2 * i]     = (bf16_t)(-r0 * n0 + p0 * c0);
    row[64 + 2 * i + 1] = (bf16_t)(-r1 * n1 + p1 * c1);
}

// ---------------------------------------------------------------------------
// Flash attention v3 (unchanged). Block = (16 q-rows, 1 kv-head, 4 q-heads).
// ---------------------------------------------------------------------------
__global__ __launch_bounds__(256, 2) void flash_attn3(
    const bf16_t* Q, const bf16_t* __restrict__ Kb,
    const bf16_t* __restrict__ VT, bf16_t* O, int S)
{
    __shared__ __align__(16) bf16_t sK[64 * 136];
    __shared__ __align__(16) bf16_t sVT[128 * 72];
    __shared__ __align__(16) bf16_t sP[4][16 * 72];

    const int kvh = blockIdx.y;
    const int q0  = blockIdx.x * 16;
    const int tid = threadIdx.x, lane = tid & 63, wave = tid >> 6;
    const int l16 = lane & 15, quad = lane >> 4;
    const int head = kvh * 4 + wave;
    const float scale = 0.08838834764831845f;  // 1/sqrt(128)

    bf16x8 qf[4];
#pragma unroll
    for (int c = 0; c < 4; c++)
        qf[c] = *(const bf16x8*)&Q[(size_t)(q0 + l16) * HID + head * HD + c * 32 + quad * 8];

    f32x4 oacc[8] = {};
    float lsum[4] = {};
    const int s_row = q0 + quad * 4;
    const int nkt = (blockIdx.x >> 2) + 1;

    int krow[4], kcol[4], vrow[4], vcol[4];
#pragma unroll
    for (int it = 0; it < 4; it++) {
        int c = tid + 256 * it;
        krow[it] = c >> 4; kcol[it] = (c & 15) * 8;
        vrow[it] = c >> 3; vcol[it] = (c & 7) * 8;
    }

    bf16x8 kpre[4], vpre[4];
#pragma unroll
    for (int it = 0; it < 4; it++) {
        kpre[it] = *(const bf16x8*)&Kb[(size_t)krow[it] * (NKV * HD) + kvh * HD + kcol[it]];
        vpre[it] = *(const bf16x8*)&VT[((size_t)kvh * HD + vrow[it]) * S + vcol[it]];
    }

    for (int kt = 0; kt < nkt; kt++) {
        const int t0 = kt * 64;
        __syncthreads();
#pragma unroll
        for (int it = 0; it < 4; it++) {
            *(bf16x8*)&sK[krow[it] * 136 + kcol[it]] = kpre[it];
            *(bf16x8*)&sVT[vrow[it] * 72 + vcol[it]] = vpre[it];
        }
        __syncthreads();

        if (kt + 1 < nkt) {
            const int t1 = t0 + 64;
#pragma unroll
            for (int it = 0; it < 4; it++) {
                kpre[it] = *(const bf16x8*)&Kb[(size_t)(t1 + krow[it]) * (NKV * HD) + kvh * HD + kcol[it]];
                vpre[it] = *(const bf16x8*)&VT[((size_t)kvh * HD + vrow[it]) * S + t1 + vcol[it]];
            }
        }

        f32x4 sc[4];
#pragma unroll
        for (int nt = 0; nt < 4; nt++) {
            f32x4 d = {};
#pragma unroll
            for (int c = 0; c < 4; c++) {
                bf16x8 kf = *(bf16x8*)&sK[(nt * 16 + l16) * 136 + c * 32 + quad * 8];
                d = __builtin_amdgcn_mfma_f32_16x16x32_bf16(qf[c], kf, d, 0, 0, 0);
            }
            sc[nt] = d;
        }

#pragma unroll
        for (int nt = 0; nt < 4; nt++) {
            int t = t0 + nt * 16 + l16;
#pragma unroll
            for (int r = 0; r < 4; r++) {
                float p = (t <= s_row + r) ? __expf(sc[nt][r] * scale) : 0.0f;
                lsum[r] += p;
                sP[wave][(quad * 4 + r) * 72 + nt * 16 + l16] = (bf16_t)p;
            }
        }
        bf16x8 pa[2];
#pragma unroll
        for (int kc = 0; kc < 2; kc++)
            pa[kc] = *(bf16x8*)&sP[wave][l16 * 72 + kc * 32 + quad * 8];

#pragma unroll
        for (int dt = 0; dt < 8; dt++)
#pragma unroll
            for (int kc = 0; kc < 2; kc++) {
                bf16x8 vf = *(bf16x8*)&sVT[(dt * 16 + l16) * 72 + kc * 32 + quad * 8];
                oacc[dt] = __builtin_amdgcn_mfma_f32_16x16x32_bf16(pa[kc], vf, oacc[dt], 0, 0, 0);
            }
    }

#pragma unroll
    for (int r = 0; r < 4; r++) {
        float s = lsum[r];
        for (int m = 1; m < 16; m <<= 1)
            s += __shfl_xor(s, m, 64);
        float inv = 1.0f / s;
        int srow = s_row + r;
#pragma unroll
        for (int dt = 0; dt < 8; dt++)
            O[(size_t)srow * HID + head * HD + dt * 16 + l16] = (bf16_t)(oacc[dt][r] * inv);
    }
}

// ---------------------------------------------------------------------------
extern "C" void kernel_launch(void* const* d_in, const int* in_sizes, int n_in,
                              void* d_out, int out_size, void* d_ws, size_t ws_size,
                              hipStream_t stream)
{
    const float* x    = (const float*)d_in[0];
    const float* cosb = (const float*)d_in[1];
    const float* sinb = (const float*)d_in[2];
    const float* wq   = (const float*)d_in[3];
    const float* wk   = (const float*)d_in[4];
    const float* wv   = (const float*)d_in[5];
    const float* wo   = (const float*)d_in[6];
    float* out = (float*)d_out;

    // Workspace (24 MB):
    char* ws = (char*)d_ws;
    bf16_t* wb = (bf16_t*)(ws);                              // 0..12 MB: [wq;wk;wv] bf16 (reused for wo)
    bf16_t* qh = (bf16_t*)(ws + (size_t)12 * 1024 * 1024);   // 12..20 MB: q / attn-out
    bf16_t* kh = (bf16_t*)(ws + (size_t)20 * 1024 * 1024);   // 20..22 MB: k
    bf16_t* vT = (bf16_t*)(ws + (size_t)22 * 1024 * 1024);   // 22..24 MB: v^T
    // x bf16 lives in d_out's first 8 MB (dead before final GEMM writes it)
    bf16_t* xb = (bf16_t*)d_out;

    const int NX = S_LEN * HID;   // 4 Mi

    // 1) x -> bf16 (into d_out scratch)
    cvt_f32_bf16<<<NX / (256 * 8), 256, 0, stream>>>(x, xb, NX);

    // 2) weights -> bf16
    cvt_w3<<<6 * 1024 * 1024 / (256 * 8), 256, 0, stream>>>(wq, wk, wv, wb);

    // 3) fused QKV GEMM (all-bf16, m97 recipe), routed outputs. grid 24x16.
    gemm128<1, bf16_t><<<dim3(24, 16), 256, 0, stream>>>(xb, wb, qh, kh, vT, 3072, HID);

    // 4) RoPE on q + k
    rope_all<<<dim3(S_LEN, 5), 128, 0, stream>>>(qh, kh, cosb, sinb);

    // 5) causal GQA flash attention (O aliases Q)
    flash_attn3<<<dim3(S_LEN / 16, NKV), 256, 0, stream>>>(qh, kh, vT, qh, S_LEN);

    // 6) wo -> bf16 (reuses wb; xb in d_out is dead after step 3)
    cvt_f32_bf16<<<NX / (256 * 8), 256, 0, stream>>>(wo, wb, NX);

    // 7) out = attn_out @ wo^T -> fp32 d_out (overwrites xb scratch). grid 16x16.
    gemm128<0, float><<<dim3(16, 16), 256, 0, stream>>>(qh, wb, out, nullptr, nullptr, HID, HID);
}